// Round 1
// baseline (623.615 us; speedup 1.0000x reference)
//
#include <hip/hip_runtime.h>
#include <hip/hip_bf16.h>

// Problem constants
#define KDIM   2048     // IN_DIM (contraction)
#define DDIM   2048     // OUT_DIM
#define MROWS  16384    // BATCH*SEQ
#define BASIS  64
#define EPSLN  1e-5f

typedef __bf16 bf16x8 __attribute__((ext_vector_type(8)));
typedef float  f32x4  __attribute__((ext_vector_type(4)));

static __device__ __forceinline__ unsigned short f2bf(float f) {
  union { float f; unsigned int u; } v; v.f = f;
  unsigned int r = v.u + 0x7FFFu + ((v.u >> 16) & 1u);  // RNE
  return (unsigned short)(r >> 16);
}

// ---------------- cast fp32 -> bf16 (vectorized, grid-stride) ----------------
__global__ __launch_bounds__(256) void cast_f32_bf16(
    const float* __restrict__ in, unsigned short* __restrict__ out, int n4) {
  int i = blockIdx.x * blockDim.x + threadIdx.x;
  int stride = gridDim.x * blockDim.x;
  for (; i < n4; i += stride) {
    float4 v = ((const float4*)in)[i];
    ushort4 o;
    o.x = f2bf(v.x); o.y = f2bf(v.y); o.z = f2bf(v.z); o.w = f2bf(v.w);
    ((ushort4*)out)[i] = o;
  }
}

// ---------------- Acoeff (D,64) -> At (64,D) so epilogue reads coalesced ----
__global__ __launch_bounds__(256) void transpose_acoeff(
    const float* __restrict__ Ac, float* __restrict__ At) {
  int j = blockIdx.x;  // 0..63
  for (int d = threadIdx.x; d < DDIM; d += blockDim.x)
    At[j * DDIM + d] = Ac[d * BASIS + j];
}

// ---------------- global -> LDS direct (16B/lane) ----------------------------
__device__ __forceinline__ void gload16(const void* g, void* l) {
  __builtin_amdgcn_global_load_lds(
      (const __attribute__((address_space(1))) unsigned int*)(unsigned long long)g,
      (__attribute__((address_space(3))) unsigned int*)(unsigned int)(unsigned long long)l,
      16, 0, 0);
}

// ---------------- dual GEMM: T = x*W^T (-> Tout), R = x*Wres^T (-> Rout) ----
// B-operand is Wc = concat(W, Wres): 4096 rows x 2048 k, row-major (N,K).
// 128x128 tile, BK=64, 4 waves (2x2), 16x16x32 bf16 MFMA.
// LDS layout [row][k-octet-slot], slot XOR-swizzled by (row&7) via pre-swizzled
// global source (global_load_lds dest must stay linear).
__global__ __launch_bounds__(256) void gemm_dual(
    const unsigned short* __restrict__ Abf,   // MROWS x KDIM
    const unsigned short* __restrict__ Bbf,   // 4096 x KDIM
    float* __restrict__ Tout,                 // MROWS x DDIM
    float* __restrict__ Rout)                 // MROWS x DDIM
{
  __shared__ __align__(16) unsigned short As[128 * 64];
  __shared__ __align__(16) unsigned short Bs[128 * 64];

  const int tid   = threadIdx.x;
  const int lane  = tid & 63;
  const int wave  = tid >> 6;
  const int bx    = blockIdx.x;      // 0..31  (concat-N)
  const int by    = blockIdx.y;      // 0..127 (M)
  const int brow0 = by * 128;
  const int bcol0 = bx * 128;

  // staging: lane covers row=lane>>3 (of 8-row/wave chunk), k-octet slot=lane&7
  // source octet pre-swizzled so LDS holds lds[row][s] = octet (s ^ (row&7))
  const int srow  = lane >> 3;
  const int sslot = (lane & 7) ^ srow;
  const unsigned short* pA = Abf + (size_t)(brow0 + wave * 8 + srow) * KDIM + sslot * 8;
  const unsigned short* pB = Bbf + (size_t)(bcol0 + wave * 8 + srow) * KDIM + sslot * 8;

  // fragment-read constants
  const int wm   = wave >> 1;        // wave row 0..1 (64 rows each)
  const int wn   = wave & 1;         // wave col 0..1
  const int frow = lane & 15;
  const int kgrp = lane >> 4;        // 0..3
  const int swz  = lane & 7;         // == (frag row)&7

  f32x4 acc[4][4] = {};

  for (int kt = 0; kt < KDIM; kt += 64) {
#pragma unroll
    for (int c = 0; c < 4; ++c) {
      gload16(pA + (size_t)c * 32 * KDIM + kt, As + c * 2048 + wave * 512);
      gload16(pB + (size_t)c * 32 * KDIM + kt, Bs + c * 2048 + wave * 512);
    }
    __syncthreads();   // drains vmcnt(0): staged tile visible
#pragma unroll
    for (int ko = 0; ko < 8; ko += 4) {   // two K=32 MFMA chunks in BK=64
      bf16x8 af[4], bv[4];
#pragma unroll
      for (int i = 0; i < 4; ++i) {
        int row = wm * 64 + i * 16 + frow;
        af[i] = *(const bf16x8*)((const char*)As + row * 128 + (((ko + kgrp) ^ swz) * 16));
      }
#pragma unroll
      for (int j = 0; j < 4; ++j) {
        int row = wn * 64 + j * 16 + frow;
        bv[j] = *(const bf16x8*)((const char*)Bs + row * 128 + (((ko + kgrp) ^ swz) * 16));
      }
#pragma unroll
      for (int i = 0; i < 4; ++i)
#pragma unroll
        for (int j = 0; j < 4; ++j)
          acc[i][j] = __builtin_amdgcn_mfma_f32_16x16x32_bf16(af[i], bv[j], acc[i][j], 0, 0, 0);
    }
    __syncthreads();   // all reads done before next-tile overwrite
  }

  // C write: col = lane&15, row = (lane>>4)*4 + reg   [m89-verified layout]
  float* Cb   = (bx < 16) ? Tout : Rout;
  const int c0 = (bx < 16) ? bcol0 : (bcol0 - 2048);
#pragma unroll
  for (int i = 0; i < 4; ++i) {
    const int r0 = brow0 + wm * 64 + i * 16 + kgrp * 4;
#pragma unroll
    for (int j = 0; j < 4; ++j) {
      const int col = c0 + wn * 64 + j * 16 + frow;
#pragma unroll
      for (int r = 0; r < 4; ++r)
        Cb[(size_t)(r0 + r) * DDIM + col] = acc[i][j][r];
    }
  }
}

// ---------------- epilogue: LayerNorm -> scalar -> out = scalar*A + residual -
// One block (256 thr) per (b,s) row. d_out already holds residual from GEMM.
__global__ __launch_bounds__(256) void epilogue(
    const float* __restrict__ T, const float* __restrict__ Bb,
    const float* __restrict__ At, const float* __restrict__ gam,
    const float* __restrict__ bet, float* __restrict__ out)
{
  __shared__ float red[16];
  const int row = blockIdx.x;          // 0..16383
  const int s   = row & 4095;
  const int j   = s & 63;
  const int tid = threadIdx.x;
  const size_t rb = (size_t)row * DDIM;
  const int d0 = tid * 8;

  float4 t0 = *(const float4*)(T + rb + d0);
  float4 t1 = *(const float4*)(T + rb + d0 + 4);

  float sum = t0.x + t0.y + t0.z + t0.w + t1.x + t1.y + t1.z + t1.w;
  float sq  = t0.x*t0.x + t0.y*t0.y + t0.z*t0.z + t0.w*t0.w
            + t1.x*t1.x + t1.y*t1.y + t1.z*t1.z + t1.w*t1.w;
#pragma unroll
  for (int off = 32; off > 0; off >>= 1) {
    sum += __shfl_down(sum, off);
    sq  += __shfl_down(sq,  off);
  }
  if ((tid & 63) == 0) { red[tid >> 6] = sum; red[4 + (tid >> 6)] = sq; }
  __syncthreads();
  if (tid == 0) {
    float sAll = red[0] + red[1] + red[2] + red[3];
    float qAll = red[4] + red[5] + red[6] + red[7];
    float m = sAll * (1.0f / 2048.0f);
    float v = qAll * (1.0f / 2048.0f) - m * m;
    red[8] = m;
    red[9] = rsqrtf(v + EPSLN);
  }
  __syncthreads();
  const float mean = red[8], rstd = red[9];

  const size_t jb = (size_t)j * DDIM;
  float4 g0 = *(const float4*)(gam + d0), g1 = *(const float4*)(gam + d0 + 4);
  float4 b0 = *(const float4*)(bet + d0), b1 = *(const float4*)(bet + d0 + 4);
  float4 w0 = *(const float4*)(Bb + jb + d0), w1 = *(const float4*)(Bb + jb + d0 + 4);

  float sc =
      ((t0.x - mean) * rstd * g0.x + b0.x) * w0.x +
      ((t0.y - mean) * rstd * g0.y + b0.y) * w0.y +
      ((t0.z - mean) * rstd * g0.z + b0.z) * w0.z +
      ((t0.w - mean) * rstd * g0.w + b0.w) * w0.w +
      ((t1.x - mean) * rstd * g1.x + b1.x) * w1.x +
      ((t1.y - mean) * rstd * g1.y + b1.y) * w1.y +
      ((t1.z - mean) * rstd * g1.z + b1.z) * w1.z +
      ((t1.w - mean) * rstd * g1.w + b1.w) * w1.w;
#pragma unroll
  for (int off = 32; off > 0; off >>= 1) sc += __shfl_down(sc, off);
  if ((tid & 63) == 0) red[10 + (tid >> 6)] = sc;
  __syncthreads();
  const float scalar = red[10] + red[11] + red[12] + red[13];

  float4 a0 = *(const float4*)(At + jb + d0), a1 = *(const float4*)(At + jb + d0 + 4);
  float4 o0 = *(const float4*)(out + rb + d0), o1 = *(const float4*)(out + rb + d0 + 4);
  o0.x = scalar * a0.x + o0.x;  o0.y = scalar * a0.y + o0.y;
  o0.z = scalar * a0.z + o0.z;  o0.w = scalar * a0.w + o0.w;
  o1.x = scalar * a1.x + o1.x;  o1.y = scalar * a1.y + o1.y;
  o1.z = scalar * a1.z + o1.z;  o1.w = scalar * a1.w + o1.w;
  *(float4*)(out + rb + d0)     = o0;
  *(float4*)(out + rb + d0 + 4) = o1;
}

// ---------------- launch ------------------------------------------------------
extern "C" void kernel_launch(void* const* d_in, const int* in_sizes, int n_in,
                              void* d_out, int out_size, void* d_ws, size_t ws_size,
                              hipStream_t stream) {
  const float* x      = (const float*)d_in[0];
  const float* W      = (const float*)d_in[1];
  const float* Wres   = (const float*)d_in[2];
  const float* gamma  = (const float*)d_in[3];
  const float* beta   = (const float*)d_in[4];
  const float* Acoeff = (const float*)d_in[5];
  const float* Bbasis = (const float*)d_in[6];
  float* out = (float*)d_out;
  char* ws = (char*)d_ws;

  // ws layout (bytes):
  //   [0,            67108864)  x_bf16   16384x2048 bf16
  //   [67108864,     83886080)  Wc_bf16  4096x2048 bf16 (W then W_res)
  //   [83886080,    218103808)  T        16384x2048 f32
  //   [218103808,   218628096)  At       64x2048 f32
  unsigned short* xbf = (unsigned short*)ws;
  unsigned short* Wc  = (unsigned short*)(ws + 67108864);
  float* T            = (float*)(ws + 83886080);
  float* At           = (float*)(ws + 218103808);

  cast_f32_bf16<<<2048, 256, 0, stream>>>(x,    xbf,            8388608);
  cast_f32_bf16<<<512,  256, 0, stream>>>(W,    Wc,             1048576);
  cast_f32_bf16<<<512,  256, 0, stream>>>(Wres, Wc + 4194304,   1048576);
  transpose_acoeff<<<64, 256, 0, stream>>>(Acoeff, At);

  dim3 grid(32, 128);   // (concat-N blocks, M blocks)
  gemm_dual<<<grid, 256, 0, stream>>>(xbf, Wc, T, out);

  epilogue<<<16384, 256, 0, stream>>>(T, Bbasis, At, gamma, beta, out);
}

// Round 2
// 612.158 us; speedup vs baseline: 1.0187x; 1.0187x over previous
//
#include <hip/hip_runtime.h>
#include <hip/hip_bf16.h>

// Problem constants
#define KDIM   2048     // IN_DIM (contraction)
#define DDIM   2048     // OUT_DIM
#define MROWS  16384    // BATCH*SEQ
#define BASIS  64
#define EPSLN  1e-5f
#define NKT    32       // K tiles of 64

typedef __bf16 bf16x8 __attribute__((ext_vector_type(8)));
typedef float  f32x4  __attribute__((ext_vector_type(4)));
typedef unsigned short u16x8 __attribute__((ext_vector_type(8)));

static __device__ __forceinline__ unsigned short f2bf(float f) {
  union { float f; unsigned int u; } v; v.f = f;
  unsigned int r = v.u + 0x7FFFu + ((v.u >> 16) & 1u);  // RNE
  return (unsigned short)(r >> 16);
}
static __device__ __forceinline__ float bf2f(unsigned short h) {
  union { unsigned int u; float f; } v; v.u = ((unsigned int)h) << 16;
  return v.f;
}

// ---------------- cast fp32 -> bf16 (vectorized, grid-stride) ----------------
__global__ __launch_bounds__(256) void cast_f32_bf16(
    const float* __restrict__ in, unsigned short* __restrict__ out, int n4) {
  int i = blockIdx.x * blockDim.x + threadIdx.x;
  int stride = gridDim.x * blockDim.x;
  for (; i < n4; i += stride) {
    float4 v = ((const float4*)in)[i];
    ushort4 o;
    o.x = f2bf(v.x); o.y = f2bf(v.y); o.z = f2bf(v.z); o.w = f2bf(v.w);
    ((ushort4*)out)[i] = o;
  }
}

// ---------------- Acoeff (D,64) -> At (64,D) so epilogue reads coalesced ----
__global__ __launch_bounds__(256) void transpose_acoeff(
    const float* __restrict__ Ac, float* __restrict__ At) {
  int j = blockIdx.x;  // 0..63
  for (int d = threadIdx.x; d < DDIM; d += blockDim.x)
    At[j * DDIM + d] = Ac[d * BASIS + j];
}

// ---------------- global -> LDS direct (16B/lane, wave-uniform LDS base) ----
__device__ __forceinline__ void gload16(const void* g, void* l) {
  __builtin_amdgcn_global_load_lds(
      (const __attribute__((address_space(1))) unsigned int*)(unsigned long long)g,
      (__attribute__((address_space(3))) unsigned int*)(unsigned int)(unsigned long long)l,
      16, 0, 0);
}

__device__ __forceinline__ void bar() {
  asm volatile("s_barrier" ::: "memory");
}

// ---------------- dual GEMM, 256x256 tile, 8-phase-style schedule ------------
// B-operand Wc = concat(W, W_res): 4096 x 2048 bf16 row-major (N,K).
// 8 waves (2M x 4N), per-wave C = 128x64 = acc[8][4] f32x4.
// LDS: 2-deep double buffer, [2][256][64] bf16 per matrix = 128 KiB total.
// Swizzle: LDS[row][slot] = global octet (slot ^ (row&7)) — 0 bank conflicts
// (verified round 1); linear LDS dest + pre-swizzled global source (rule #21).
// Counted vmcnt(8): tile kt+2's 8 loads issued at iter end; 16 in flight at
// iter start, wait only the oldest 8 (never drain to 0 in the main loop).
__global__ __launch_bounds__(512, 2) void gemm_dual(
    const unsigned short* __restrict__ Abf,   // MROWS x KDIM
    const unsigned short* __restrict__ Bbf,   // 4096 x KDIM
    unsigned short* __restrict__ Tout,        // MROWS x DDIM (bf16)
    float* __restrict__ Rout)                 // MROWS x DDIM (f32, residual)
{
  __shared__ __align__(16) unsigned short As[2 * 256 * 64];
  __shared__ __align__(16) unsigned short Bs[2 * 256 * 64];

  const int tid  = threadIdx.x;
  const int lane = tid & 63;
  const int wave = tid >> 6;

  // XCD-aware bijective swizzle (nwg=1024, %8==0)
  const int bid = blockIdx.x;
  const int wg  = (bid & 7) * 128 + (bid >> 3);
  const int bm  = wg >> 4;          // 0..63  (M)
  const int bn  = wg & 15;          // 0..15  (concat-N)
  const int brow0 = bm * 256;
  const int bcol0 = bn * 256;

  // staging: thread t covers row (t>>3) of each 64-row round, octet slot t&7,
  // global source octet pre-swizzled by row&7
  const int srow  = tid >> 3;                    // 0..63
  const int sslot = (tid & 7) ^ (srow & 7);
  const unsigned short* pA = Abf + (size_t)(brow0 + srow) * KDIM + sslot * 8;
  const unsigned short* pB = Bbf + (size_t)(bcol0 + srow) * KDIM + sslot * 8;
  const int ldst = wave * 512;                   // wave-uniform LDS base (ushorts/round)

  // fragment constants
  const int wm   = wave >> 2;        // 0..1
  const int wn   = wave & 3;         // 0..3
  const int frow = lane & 15;
  const int kgrp = lane >> 4;        // 0..3
  const int swz  = frow & 7;

  f32x4 acc[8][4] = {};

  // prologue: stage tile 0 -> buf0, tile 1 -> buf1 (16 loads outstanding)
#pragma unroll
  for (int c = 0; c < 4; ++c) {
    gload16(pA + (size_t)c * 64 * KDIM,      As + c * 4096 + ldst);
    gload16(pB + (size_t)c * 64 * KDIM,      Bs + c * 4096 + ldst);
  }
#pragma unroll
  for (int c = 0; c < 4; ++c) {
    gload16(pA + (size_t)c * 64 * KDIM + 64, As + 16384 + c * 4096 + ldst);
    gload16(pB + (size_t)c * 64 * KDIM + 64, Bs + 16384 + c * 4096 + ldst);
  }

  for (int kt = 0; kt < NKT; ++kt) {
    const unsigned short* As_b = As + (kt & 1) * 16384;
    const unsigned short* Bs_b = Bs + (kt & 1) * 16384;

    // wait for tile kt's 8 loads (oldest); leave tile kt+1's 8 in flight
    if (kt < NKT - 1) { asm volatile("s_waitcnt vmcnt(8)" ::: "memory"); }
    else              { asm volatile("s_waitcnt vmcnt(0)" ::: "memory"); }
    __builtin_amdgcn_sched_barrier(0);
    bar();

#pragma unroll
    for (int ko = 0; ko < 2; ++ko) {
      bf16x8 bv[4], af[4];
      // ---- phase h=0: 8 ds_read_b128 (4 B-frags + 4 A-frags), 16 MFMA ----
#pragma unroll
      for (int j = 0; j < 4; ++j) {
        const int row = wn * 64 + j * 16 + frow;
        bv[j] = *(const bf16x8*)(Bs_b + row * 64 + (((ko * 4 + kgrp) ^ swz) << 3));
      }
#pragma unroll
      for (int i = 0; i < 4; ++i) {
        const int row = wm * 128 + i * 16 + frow;
        af[i] = *(const bf16x8*)(As_b + row * 64 + (((ko * 4 + kgrp) ^ swz) << 3));
      }
      bar();
      __builtin_amdgcn_s_setprio(1);
#pragma unroll
      for (int i = 0; i < 4; ++i)
#pragma unroll
        for (int j = 0; j < 4; ++j)
          acc[i][j] = __builtin_amdgcn_mfma_f32_16x16x32_bf16(af[i], bv[j], acc[i][j], 0, 0, 0);
      __builtin_amdgcn_s_setprio(0);
      bar();
      // ---- phase h=1: 4 ds_read_b128 (A-frags i=4..7, reuse bv), 16 MFMA ---
#pragma unroll
      for (int i = 0; i < 4; ++i) {
        const int row = wm * 128 + 64 + i * 16 + frow;
        af[i] = *(const bf16x8*)(As_b + row * 64 + (((ko * 4 + kgrp) ^ swz) << 3));
      }
      bar();
      __builtin_amdgcn_s_setprio(1);
#pragma unroll
      for (int i = 0; i < 4; ++i)
#pragma unroll
        for (int j = 0; j < 4; ++j)
          acc[4 + i][j] = __builtin_amdgcn_mfma_f32_16x16x32_bf16(af[i], bv[j], acc[4 + i][j], 0, 0, 0);
      __builtin_amdgcn_s_setprio(0);
      bar();
    }

    // stage tile kt+2 into buf (kt&1) — safe: all reads of this buf completed
    // (post-MFMA barrier above), and it's not read during iter kt+1
    if (kt + 2 < NKT) {
      unsigned short* Ad = As + (kt & 1) * 16384;
      unsigned short* Bd = Bs + (kt & 1) * 16384;
      const int k64 = (kt + 2) * 64;
#pragma unroll
      for (int c = 0; c < 4; ++c) {
        gload16(pA + (size_t)c * 64 * KDIM + k64, Ad + c * 4096 + ldst);
        gload16(pB + (size_t)c * 64 * KDIM + k64, Bd + c * 4096 + ldst);
      }
    }
  }

  // C write: col = lane&15, row = (lane>>4)*4 + reg   [verified round 1]
  if (bn < 8) {
    unsigned short* Cb = Tout;
    const int c0 = bcol0;
#pragma unroll
    for (int i = 0; i < 8; ++i) {
      const int r0 = brow0 + wm * 128 + i * 16 + kgrp * 4;
#pragma unroll
      for (int j = 0; j < 4; ++j) {
        const int col = c0 + wn * 64 + j * 16 + frow;
#pragma unroll
        for (int r = 0; r < 4; ++r)
          Cb[(size_t)(r0 + r) * DDIM + col] = f2bf(acc[i][j][r]);
      }
    }
  } else {
    float* Cb = Rout;
    const int c0 = bcol0 - 2048;
#pragma unroll
    for (int i = 0; i < 8; ++i) {
      const int r0 = brow0 + wm * 128 + i * 16 + kgrp * 4;
#pragma unroll
      for (int j = 0; j < 4; ++j) {
        const int col = c0 + wn * 64 + j * 16 + frow;
#pragma unroll
        for (int r = 0; r < 4; ++r)
          Cb[(size_t)(r0 + r) * DDIM + col] = acc[i][j][r];
      }
    }
  }
}

// ---------------- epilogue: LayerNorm -> scalar -> out = scalar*A + residual -
// One block (256 thr) per (b,s) row. d_out already holds residual from GEMM.
__global__ __launch_bounds__(256) void epilogue(
    const unsigned short* __restrict__ T, const float* __restrict__ Bb,
    const float* __restrict__ At, const float* __restrict__ gam,
    const float* __restrict__ bet, float* __restrict__ out)
{
  __shared__ float red[16];
  const int row = blockIdx.x;          // 0..16383
  const int s   = row & 4095;
  const int j   = s & 63;
  const int tid = threadIdx.x;
  const size_t rb = (size_t)row * DDIM;
  const int d0 = tid * 8;

  u16x8 tv = *(const u16x8*)(T + rb + d0);
  float t[8];
#pragma unroll
  for (int k = 0; k < 8; ++k) t[k] = bf2f(tv[k]);

  float sum = 0.f, sq = 0.f;
#pragma unroll
  for (int k = 0; k < 8; ++k) { sum += t[k]; sq += t[k] * t[k]; }
#pragma unroll
  for (int off = 32; off > 0; off >>= 1) {
    sum += __shfl_down(sum, off);
    sq  += __shfl_down(sq,  off);
  }
  if ((tid & 63) == 0) { red[tid >> 6] = sum; red[4 + (tid >> 6)] = sq; }
  __syncthreads();
  if (tid == 0) {
    float sAll = red[0] + red[1] + red[2] + red[3];
    float qAll = red[4] + red[5] + red[6] + red[7];
    float m = sAll * (1.0f / 2048.0f);
    float v = qAll * (1.0f / 2048.0f) - m * m;
    red[8] = m;
    red[9] = rsqrtf(v + EPSLN);
  }
  __syncthreads();
  const float mean = red[8], rstd = red[9];

  const size_t jb = (size_t)j * DDIM;
  float4 g0 = *(const float4*)(gam + d0), g1 = *(const float4*)(gam + d0 + 4);
  float4 b0 = *(const float4*)(bet + d0), b1 = *(const float4*)(bet + d0 + 4);
  float4 w0 = *(const float4*)(Bb + jb + d0), w1 = *(const float4*)(Bb + jb + d0 + 4);

  float sc =
      ((t[0] - mean) * rstd * g0.x + b0.x) * w0.x +
      ((t[1] - mean) * rstd * g0.y + b0.y) * w0.y +
      ((t[2] - mean) * rstd * g0.z + b0.z) * w0.z +
      ((t[3] - mean) * rstd * g0.w + b0.w) * w0.w +
      ((t[4] - mean) * rstd * g1.x + b1.x) * w1.x +
      ((t[5] - mean) * rstd * g1.y + b1.y) * w1.y +
      ((t[6] - mean) * rstd * g1.z + b1.z) * w1.z +
      ((t[7] - mean) * rstd * g1.w + b1.w) * w1.w;
#pragma unroll
  for (int off = 32; off > 0; off >>= 1) sc += __shfl_down(sc, off);
  if ((tid & 63) == 0) red[10 + (tid >> 6)] = sc;
  __syncthreads();
  const float scalar = red[10] + red[11] + red[12] + red[13];

  float4 a0 = *(const float4*)(At + jb + d0), a1 = *(const float4*)(At + jb + d0 + 4);
  float4 o0 = *(const float4*)(out + rb + d0), o1 = *(const float4*)(out + rb + d0 + 4);
  o0.x = scalar * a0.x + o0.x;  o0.y = scalar * a0.y + o0.y;
  o0.z = scalar * a0.z + o0.z;  o0.w = scalar * a0.w + o0.w;
  o1.x = scalar * a1.x + o1.x;  o1.y = scalar * a1.y + o1.y;
  o1.z = scalar * a1.z + o1.z;  o1.w = scalar * a1.w + o1.w;
  *(float4*)(out + rb + d0)     = o0;
  *(float4*)(out + rb + d0 + 4) = o1;
}

// ---------------- launch ------------------------------------------------------
extern "C" void kernel_launch(void* const* d_in, const int* in_sizes, int n_in,
                              void* d_out, int out_size, void* d_ws, size_t ws_size,
                              hipStream_t stream) {
  const float* x      = (const float*)d_in[0];
  const float* W      = (const float*)d_in[1];
  const float* Wres   = (const float*)d_in[2];
  const float* gamma  = (const float*)d_in[3];
  const float* beta   = (const float*)d_in[4];
  const float* Acoeff = (const float*)d_in[5];
  const float* Bbasis = (const float*)d_in[6];
  float* out = (float*)d_out;
  char* ws = (char*)d_ws;

  // ws layout (bytes):
  //   [0,           67108864)  x_bf16   16384x2048 bf16
  //   [67108864,    83886080)  Wc_bf16  4096x2048 bf16 (W then W_res)
  //   [83886080,   150994944)  T        16384x2048 bf16
  //   [150994944,  151519232)  At       64x2048 f32
  unsigned short* xbf = (unsigned short*)ws;
  unsigned short* Wc  = (unsigned short*)(ws + 67108864);
  unsigned short* T   = (unsigned short*)(ws + 83886080);
  float* At           = (float*)(ws + 150994944);

  cast_f32_bf16<<<2048, 256, 0, stream>>>(x,    xbf,            8388608);
  cast_f32_bf16<<<512,  256, 0, stream>>>(W,    Wc,             1048576);
  cast_f32_bf16<<<512,  256, 0, stream>>>(Wres, Wc + 4194304,   1048576);
  transpose_acoeff<<<64, 256, 0, stream>>>(Acoeff, At);

  gemm_dual<<<1024, 512, 0, stream>>>(xbf, Wc, T, out);

  epilogue<<<16384, 256, 0, stream>>>(T, Bbasis, At, gamma, beta, out);
}

// Round 3
// 538.947 us; speedup vs baseline: 1.1571x; 1.1358x over previous
//
#include <hip/hip_runtime.h>
#include <hip/hip_bf16.h>

// Problem constants
#define KDIM   2048     // IN_DIM (contraction)
#define DDIM   2048     // OUT_DIM
#define MROWS  16384    // BATCH*SEQ
#define BASIS  64
#define EPSLN  1e-5f
#define NKT    32       // K tiles of 64

typedef __bf16 bf16x8 __attribute__((ext_vector_type(8)));
typedef float  f32x4  __attribute__((ext_vector_type(4)));
typedef unsigned short u16x8 __attribute__((ext_vector_type(8)));

static __device__ __forceinline__ unsigned short f2bf(float f) {
  union { float f; unsigned int u; } v; v.f = f;
  unsigned int r = v.u + 0x7FFFu + ((v.u >> 16) & 1u);  // RNE
  return (unsigned short)(r >> 16);
}
static __device__ __forceinline__ float bf2f(unsigned short h) {
  union { unsigned int u; float f; } v; v.u = ((unsigned int)h) << 16;
  return v.f;
}

// ---------------- fused prep: cast x/W/Wres -> bf16, transpose Acoeff --------
__global__ __launch_bounds__(256) void prep(
    const float* __restrict__ x, const float* __restrict__ W,
    const float* __restrict__ Wres, const float* __restrict__ Ac,
    unsigned short* __restrict__ xbf, unsigned short* __restrict__ Wc,
    float* __restrict__ At) {
  const int b = blockIdx.x, t = threadIdx.x;
  if (b < 2048) {            // x: 8388608 float4, 4096/block, 16/thread
    const float4* in = (const float4*)x;
    ushort4* op = (ushort4*)xbf;
    const int base = b * 4096;
#pragma unroll
    for (int k = 0; k < 16; ++k) {
      const int i = base + k * 256 + t;
      float4 v = in[i];
      op[i] = make_ushort4(f2bf(v.x), f2bf(v.y), f2bf(v.z), f2bf(v.w));
    }
  } else if (b < 3072) {     // W (blocks 2048..2559) / Wres (2560..3071)
    const bool isW = (b < 2560);
    const float4* in = (const float4*)(isW ? W : Wres);
    ushort4* op = (ushort4*)(Wc + (isW ? 0 : 4194304));
    const int base = (isW ? (b - 2048) : (b - 2560)) * 2048;
#pragma unroll
    for (int k = 0; k < 8; ++k) {
      const int i = base + k * 256 + t;
      float4 v = in[i];
      op[i] = make_ushort4(f2bf(v.x), f2bf(v.y), f2bf(v.z), f2bf(v.w));
    }
  } else {                   // Acoeff transpose: blocks 3072..3135 -> j
    const int j = b - 3072;
    for (int d = t; d < DDIM; d += 256)
      At[j * DDIM + d] = Ac[d * BASIS + j];
  }
}

// ---------------- global -> LDS direct (16B/lane, wave-uniform LDS base) ----
__device__ __forceinline__ void gload16(const void* g, void* l) {
  __builtin_amdgcn_global_load_lds(
      (const __attribute__((address_space(1))) unsigned int*)(unsigned long long)g,
      (__attribute__((address_space(3))) unsigned int*)(unsigned int)(unsigned long long)l,
      16, 0, 0);
}
__device__ __forceinline__ void bar() { asm volatile("s_barrier" ::: "memory"); }

// ---------------- dual GEMM, 256x256 tile, faithful 8-phase interleave ------
// B-operand Wc = concat(W, W_res): 4096 x 2048 bf16 row-major (N,K).
// 8 waves (2M x 4N); per-wave C = 128x64 = acc[8][4] f32x4; BK=64.
// K-tile = 4 phases (quadrant q = M-frags 2q,2q+1 x all N x K=64 -> 16 MFMA).
// Per phase: {ds-reads for quadrant | stage 1 half-tile (2 gloads) | bar |
//             setprio1 | 16 MFMA | setprio0 | sched_bar | bar}.
// Staging (tile kt+2 -> buf[kt&1], except A13 of kt+1 in ph1):
//   ph1: A chunks 1,3 of kt+1  (regions free since kt-1 ph4)
//   ph2: B chunks 0,1 of kt+2  (B free after ph1)
//   ph3: A chunks 0,2 of kt+2  (free after ph2: quadrants 0,1 read them)
//   ph4: B chunks 2,3 of kt+2
// vmcnt(6) once per K-tile at ph4 (waits tile kt+1's tail; leaves kt+2's 6).
// LDS swizzle: slot s holds global octet s^(row&7); linear dest + pre-swizzled
// source + swizzled ds_read (rule #21) — 0 bank conflicts (verified r1/r2).
__global__ __launch_bounds__(512, 2) void gemm_dual(
    const unsigned short* __restrict__ Abf,   // MROWS x KDIM
    const unsigned short* __restrict__ Bbf,   // 4096 x KDIM
    unsigned short* __restrict__ Tout,        // MROWS x DDIM (bf16)
    unsigned short* __restrict__ Rout)        // MROWS x DDIM (bf16 residual)
{
  __shared__ __align__(16) unsigned short As[2 * 256 * 64];
  __shared__ __align__(16) unsigned short Bs[2 * 256 * 64];

  const int tid  = threadIdx.x;
  const int lane = tid & 63;
  const int wave = tid >> 6;

  // XCD-aware bijective swizzle (nwg=1024, %8==0)
  const int bid = blockIdx.x;
  const int wg  = (bid & 7) * 128 + (bid >> 3);
  const int bm  = wg >> 4;          // 0..63
  const int bn  = wg & 15;          // 0..15
  const int brow0 = bm * 256;
  const int bcol0 = bn * 256;

  // staging: thread t covers row t>>3 (of a 64-row chunk), octet slot t&7;
  // global source octet pre-swizzled by row&7
  const int srow  = tid >> 3;
  const int sslot = (tid & 7) ^ (srow & 7);
  const unsigned short* pA = Abf + (size_t)(brow0 + srow) * KDIM + sslot * 8;
  const unsigned short* pB = Bbf + (size_t)(bcol0 + srow) * KDIM + sslot * 8;
  const int ldst = wave * 512;      // wave-uniform LDS offset within a chunk

  const int wm   = wave >> 2;       // 0..1
  const int wn   = wave & 3;        // 0..3
  const int frow = lane & 15;
  const int kgrp = lane >> 4;       // 0..3

#define SA(d, kk, c) gload16(pA + (size_t)(c)*64*KDIM + (kk)*64, As + (d)*16384 + (c)*4096 + ldst)
#define SB(d, kk, c) gload16(pB + (size_t)(c)*64*KDIM + (kk)*64, Bs + (d)*16384 + (c)*4096 + ldst)
  // ds-read: row*64 ushorts + swizzled 8-ushort slot; row&7 == frow&7
#define RD_A(mf, kc) (*(const bf16x8*)(Ard + (wm*128 + (mf)*16 + frow)*64 + ((((kc)*4 + kgrp) ^ (frow & 7)) << 3)))
#define RD_B(j, kc)  (*(const bf16x8*)(Brd + (wn*64  + (j)*16  + frow)*64 + ((((kc)*4 + kgrp) ^ (frow & 7)) << 3)))

  f32x4 acc[8][4] = {};

  // prologue: tile0 full -> buf0; tile1 {B01, A02, B23} -> buf1 (A13 in kt=0 ph1)
  SA(0,0,0); SA(0,0,1); SA(0,0,2); SA(0,0,3);
  SB(0,0,0); SB(0,0,1); SB(0,0,2); SB(0,0,3);
  SB(1,1,0); SB(1,1,1);
  SA(1,1,0); SA(1,1,2);
  SB(1,1,2); SB(1,1,3);
  asm volatile("s_waitcnt vmcnt(6)" ::: "memory");   // tile0's 8 landed
  __builtin_amdgcn_sched_barrier(0);
  bar();

  for (int kt = 0; kt < NKT; ++kt) {
    const int d = kt & 1;
    const unsigned short* Ard = As + d * 16384;
    const unsigned short* Brd = Bs + d * 16384;

    bf16x8 bv[4][2], af0[2], af1[2];

    // ---- phase 1 (quadrant 0): 8 B-reads + 4 A-reads | stage A13 of kt+1 ---
#pragma unroll
    for (int j = 0; j < 4; ++j) { bv[j][0] = RD_B(j, 0); bv[j][1] = RD_B(j, 1); }
    af0[0] = RD_A(0, 0); af0[1] = RD_A(0, 1);
    af1[0] = RD_A(1, 0); af1[1] = RD_A(1, 1);
    if (kt < NKT - 1) { SA(d ^ 1, kt + 1, 1); SA(d ^ 1, kt + 1, 3); }
    bar();
    __builtin_amdgcn_s_setprio(1);
#pragma unroll
    for (int j = 0; j < 4; ++j) {
      acc[0][j] = __builtin_amdgcn_mfma_f32_16x16x32_bf16(af0[0], bv[j][0], acc[0][j], 0, 0, 0);
      acc[0][j] = __builtin_amdgcn_mfma_f32_16x16x32_bf16(af0[1], bv[j][1], acc[0][j], 0, 0, 0);
      acc[1][j] = __builtin_amdgcn_mfma_f32_16x16x32_bf16(af1[0], bv[j][0], acc[1][j], 0, 0, 0);
      acc[1][j] = __builtin_amdgcn_mfma_f32_16x16x32_bf16(af1[1], bv[j][1], acc[1][j], 0, 0, 0);
    }
    __builtin_amdgcn_s_setprio(0);
    __builtin_amdgcn_sched_barrier(0);
    bar();

    // ---- phase 2 (quadrant 1): 4 A-reads | stage B01 of kt+2 ---------------
    af0[0] = RD_A(2, 0); af0[1] = RD_A(2, 1);
    af1[0] = RD_A(3, 0); af1[1] = RD_A(3, 1);
    if (kt < NKT - 2) { SB(d, kt + 2, 0); SB(d, kt + 2, 1); }
    bar();
    __builtin_amdgcn_s_setprio(1);
#pragma unroll
    for (int j = 0; j < 4; ++j) {
      acc[2][j] = __builtin_amdgcn_mfma_f32_16x16x32_bf16(af0[0], bv[j][0], acc[2][j], 0, 0, 0);
      acc[2][j] = __builtin_amdgcn_mfma_f32_16x16x32_bf16(af0[1], bv[j][1], acc[2][j], 0, 0, 0);
      acc[3][j] = __builtin_amdgcn_mfma_f32_16x16x32_bf16(af1[0], bv[j][0], acc[3][j], 0, 0, 0);
      acc[3][j] = __builtin_amdgcn_mfma_f32_16x16x32_bf16(af1[1], bv[j][1], acc[3][j], 0, 0, 0);
    }
    __builtin_amdgcn_s_setprio(0);
    __builtin_amdgcn_sched_barrier(0);
    bar();

    // ---- phase 3 (quadrant 2): 4 A-reads | stage A02 of kt+2 ---------------
    af0[0] = RD_A(4, 0); af0[1] = RD_A(4, 1);
    af1[0] = RD_A(5, 0); af1[1] = RD_A(5, 1);
    if (kt < NKT - 2) { SA(d, kt + 2, 0); SA(d, kt + 2, 2); }
    bar();
    __builtin_amdgcn_s_setprio(1);
#pragma unroll
    for (int j = 0; j < 4; ++j) {
      acc[4][j] = __builtin_amdgcn_mfma_f32_16x16x32_bf16(af0[0], bv[j][0], acc[4][j], 0, 0, 0);
      acc[4][j] = __builtin_amdgcn_mfma_f32_16x16x32_bf16(af0[1], bv[j][1], acc[4][j], 0, 0, 0);
      acc[5][j] = __builtin_amdgcn_mfma_f32_16x16x32_bf16(af1[0], bv[j][0], acc[5][j], 0, 0, 0);
      acc[5][j] = __builtin_amdgcn_mfma_f32_16x16x32_bf16(af1[1], bv[j][1], acc[5][j], 0, 0, 0);
    }
    __builtin_amdgcn_s_setprio(0);
    __builtin_amdgcn_sched_barrier(0);
    bar();

    // ---- phase 4 (quadrant 3): 4 A-reads | stage B23 of kt+2 | vmcnt -------
    af0[0] = RD_A(6, 0); af0[1] = RD_A(6, 1);
    af1[0] = RD_A(7, 0); af1[1] = RD_A(7, 1);
    if (kt < NKT - 2) { SB(d, kt + 2, 2); SB(d, kt + 2, 3); }
    bar();
    __builtin_amdgcn_s_setprio(1);
#pragma unroll
    for (int j = 0; j < 4; ++j) {
      acc[6][j] = __builtin_amdgcn_mfma_f32_16x16x32_bf16(af0[0], bv[j][0], acc[6][j], 0, 0, 0);
      acc[6][j] = __builtin_amdgcn_mfma_f32_16x16x32_bf16(af0[1], bv[j][1], acc[6][j], 0, 0, 0);
      acc[7][j] = __builtin_amdgcn_mfma_f32_16x16x32_bf16(af1[0], bv[j][0], acc[7][j], 0, 0, 0);
      acc[7][j] = __builtin_amdgcn_mfma_f32_16x16x32_bf16(af1[1], bv[j][1], acc[7][j], 0, 0, 0);
    }
    __builtin_amdgcn_s_setprio(0);
    // counted wait: tile kt+1 fully landed; tile kt+2's 6 loads stay in flight
    if (kt < NKT - 2) { asm volatile("s_waitcnt vmcnt(6)" ::: "memory"); }
    else              { asm volatile("s_waitcnt vmcnt(0)" ::: "memory"); }
    __builtin_amdgcn_sched_barrier(0);
    bar();
  }

  // C write: col = lane&15, row = (lane>>4)*4 + reg  [verified r1/r2]
  unsigned short* Cb = (bn < 8) ? Tout : Rout;
  const int c0 = (bn < 8) ? bcol0 : (bcol0 - 2048);
#pragma unroll
  for (int i = 0; i < 8; ++i) {
    const int r0 = brow0 + wm * 128 + i * 16 + kgrp * 4;
#pragma unroll
    for (int j = 0; j < 4; ++j) {
      const int col = c0 + wn * 64 + j * 16 + frow;
#pragma unroll
      for (int r = 0; r < 4; ++r)
        Cb[(size_t)(r0 + r) * DDIM + col] = f2bf(acc[i][j][r]);
    }
  }
#undef SA
#undef SB
#undef RD_A
#undef RD_B
}

// ---------------- epilogue: LayerNorm -> scalar -> out = scalar*A + residual -
__global__ __launch_bounds__(256) void epilogue(
    const unsigned short* __restrict__ T, const unsigned short* __restrict__ R,
    const float* __restrict__ Bb, const float* __restrict__ At,
    const float* __restrict__ gam, const float* __restrict__ bet,
    float* __restrict__ out)
{
  __shared__ float red[16];
  const int row = blockIdx.x;          // 0..16383
  const int s   = row & 4095;
  const int j   = s & 63;
  const int tid = threadIdx.x;
  const size_t rb = (size_t)row * DDIM;
  const int d0 = tid * 8;

  u16x8 tv = *(const u16x8*)(T + rb + d0);
  float t[8];
#pragma unroll
  for (int k = 0; k < 8; ++k) t[k] = bf2f(tv[k]);

  float sum = 0.f, sq = 0.f;
#pragma unroll
  for (int k = 0; k < 8; ++k) { sum += t[k]; sq += t[k] * t[k]; }
#pragma unroll
  for (int off = 32; off > 0; off >>= 1) {
    sum += __shfl_down(sum, off);
    sq  += __shfl_down(sq,  off);
  }
  if ((tid & 63) == 0) { red[tid >> 6] = sum; red[4 + (tid >> 6)] = sq; }
  __syncthreads();
  if (tid == 0) {
    float sAll = red[0] + red[1] + red[2] + red[3];
    float qAll = red[4] + red[5] + red[6] + red[7];
    float m = sAll * (1.0f / 2048.0f);
    float v = qAll * (1.0f / 2048.0f) - m * m;
    red[8] = m;
    red[9] = rsqrtf(v + EPSLN);
  }
  __syncthreads();
  const float mean = red[8], rstd = red[9];

  const size_t jb = (size_t)j * DDIM;
  float4 g0 = *(const float4*)(gam + d0), g1 = *(const float4*)(gam + d0 + 4);
  float4 b0 = *(const float4*)(bet + d0), b1 = *(const float4*)(bet + d0 + 4);
  float4 w0 = *(const float4*)(Bb + jb + d0), w1 = *(const float4*)(Bb + jb + d0 + 4);

  float sc =
      ((t[0] - mean) * rstd * g0.x + b0.x) * w0.x +
      ((t[1] - mean) * rstd * g0.y + b0.y) * w0.y +
      ((t[2] - mean) * rstd * g0.z + b0.z) * w0.z +
      ((t[3] - mean) * rstd * g0.w + b0.w) * w0.w +
      ((t[4] - mean) * rstd * g1.x + b1.x) * w1.x +
      ((t[5] - mean) * rstd * g1.y + b1.y) * w1.y +
      ((t[6] - mean) * rstd * g1.z + b1.z) * w1.z +
      ((t[7] - mean) * rstd * g1.w + b1.w) * w1.w;
#pragma unroll
  for (int off = 32; off > 0; off >>= 1) sc += __shfl_down(sc, off);
  if ((tid & 63) == 0) red[10 + (tid >> 6)] = sc;
  __syncthreads();
  const float scalar = red[10] + red[11] + red[12] + red[13];

  u16x8 rv = *(const u16x8*)(R + rb + d0);
  float4 a0 = *(const float4*)(At + jb + d0), a1 = *(const float4*)(At + jb + d0 + 4);
  float4 o0, o1;
  o0.x = scalar * a0.x + bf2f(rv[0]);  o0.y = scalar * a0.y + bf2f(rv[1]);
  o0.z = scalar * a0.z + bf2f(rv[2]);  o0.w = scalar * a0.w + bf2f(rv[3]);
  o1.x = scalar * a1.x + bf2f(rv[4]);  o1.y = scalar * a1.y + bf2f(rv[5]);
  o1.z = scalar * a1.z + bf2f(rv[6]);  o1.w = scalar * a1.w + bf2f(rv[7]);
  *(float4*)(out + rb + d0)     = o0;
  *(float4*)(out + rb + d0 + 4) = o1;
}

// ---------------- launch ------------------------------------------------------
extern "C" void kernel_launch(void* const* d_in, const int* in_sizes, int n_in,
                              void* d_out, int out_size, void* d_ws, size_t ws_size,
                              hipStream_t stream) {
  const float* x      = (const float*)d_in[0];
  const float* W      = (const float*)d_in[1];
  const float* Wres   = (const float*)d_in[2];
  const float* gamma  = (const float*)d_in[3];
  const float* beta   = (const float*)d_in[4];
  const float* Acoeff = (const float*)d_in[5];
  const float* Bbasis = (const float*)d_in[6];
  float* out = (float*)d_out;
  char* ws = (char*)d_ws;

  // ws layout (bytes):
  //   [0,           67108864)  x_bf16   16384x2048 bf16
  //   [67108864,    83886080)  Wc_bf16  4096x2048 bf16 (W then W_res)
  //   [83886080,   150994944)  T        16384x2048 bf16
  //   [150994944,  218103808)  Rbf      16384x2048 bf16 (residual)
  //   [218103808,  218628096)  At       64x2048 f32
  unsigned short* xbf = (unsigned short*)ws;
  unsigned short* Wc  = (unsigned short*)(ws + 67108864);
  unsigned short* T   = (unsigned short*)(ws + 83886080);
  unsigned short* Rbf = (unsigned short*)(ws + 150994944);
  float* At           = (float*)(ws + 218103808);

  prep<<<3136, 256, 0, stream>>>(x, W, Wres, Acoeff, xbf, Wc, At);

  gemm_dual<<<1024, 512, 0, stream>>>(xbf, Wc, T, Rbf);

  epilogue<<<16384, 256, 0, stream>>>(T, Rbf, Bbasis, At, gamma, beta, out);
}

// Round 6
// 535.448 us; speedup vs baseline: 1.1647x; 1.0065x over previous
//
#include <hip/hip_runtime.h>
#include <hip/hip_bf16.h>

// Problem constants
#define KDIM   2048     // IN_DIM (contraction)
#define DDIM   2048     // OUT_DIM
#define MROWS  16384    // BATCH*SEQ
#define BASIS  64
#define EPSLN  1e-5f
#define NKT    32       // K tiles of 64

typedef __bf16 bf16x8 __attribute__((ext_vector_type(8)));
typedef float  f32x4  __attribute__((ext_vector_type(4)));
typedef unsigned short u16x8 __attribute__((ext_vector_type(8)));

static __device__ __forceinline__ unsigned short f2bf(float f) {
  union { float f; unsigned int u; } v; v.f = f;
  unsigned int r = v.u + 0x7FFFu + ((v.u >> 16) & 1u);  // RNE
  return (unsigned short)(r >> 16);
}
static __device__ __forceinline__ float bf2f(unsigned short h) {
  union { unsigned int u; float f; } v; v.u = ((unsigned int)h) << 16;
  return v.f;
}

// ---------------- fused prep: cast x/W/Wres -> bf16, transpose Acoeff --------
__global__ __launch_bounds__(256) void prep(
    const float* __restrict__ x, const float* __restrict__ W,
    const float* __restrict__ Wres, const float* __restrict__ Ac,
    unsigned short* __restrict__ xbf, unsigned short* __restrict__ Wc,
    float* __restrict__ At) {
  const int b = blockIdx.x, t = threadIdx.x;
  if (b < 2048) {            // x: 8388608 float4, 4096/block, 16/thread
    const float4* in = (const float4*)x;
    ushort4* op = (ushort4*)xbf;
    const int base = b * 4096;
#pragma unroll
    for (int k = 0; k < 16; ++k) {
      const int i = base + k * 256 + t;
      float4 v = in[i];
      op[i] = make_ushort4(f2bf(v.x), f2bf(v.y), f2bf(v.z), f2bf(v.w));
    }
  } else if (b < 3072) {     // W (blocks 2048..2559) / Wres (2560..3071)
    const bool isW = (b < 2560);
    const float4* in = (const float4*)(isW ? W : Wres);
    ushort4* op = (ushort4*)(Wc + (isW ? 0 : 4194304));
    const int base = (isW ? (b - 2048) : (b - 2560)) * 2048;
#pragma unroll
    for (int k = 0; k < 8; ++k) {
      const int i = base + k * 256 + t;
      float4 v = in[i];
      op[i] = make_ushort4(f2bf(v.x), f2bf(v.y), f2bf(v.z), f2bf(v.w));
    }
  } else {                   // Acoeff transpose: blocks 3072..3135 -> j
    const int j = b - 3072;
    for (int d = t; d < DDIM; d += 256)
      At[j * DDIM + d] = Ac[d * BASIS + j];
  }
}

// ---------------- global -> LDS direct (16B/lane, wave-uniform LDS base) ----
__device__ __forceinline__ void gload16(const void* g, void* l) {
  __builtin_amdgcn_global_load_lds(
      (const __attribute__((address_space(1))) unsigned int*)(unsigned long long)g,
      (__attribute__((address_space(3))) unsigned int*)(unsigned int)(unsigned long long)l,
      16, 0, 0);
}
__device__ __forceinline__ void bar() { asm volatile("s_barrier" ::: "memory"); }
#define LGKM0 do { asm volatile("s_waitcnt lgkmcnt(0)" ::: "memory"); \
                   __builtin_amdgcn_sched_barrier(0); } while (0)

// ---------------- dual GEMM, 256x256 tile, faithful 8-phase interleave ------
// Structure identical to round 3 (verified pass) + lgkmcnt(0)+sched_barrier
// pin after each pre-MFMA barrier (adds waits only — semantically safe).
__global__ __launch_bounds__(512, 2) void gemm_dual(
    const unsigned short* __restrict__ Abf,   // MROWS x KDIM
    const unsigned short* __restrict__ Bbf,   // 4096 x KDIM
    unsigned short* __restrict__ Tout,        // MROWS x DDIM (bf16)
    unsigned short* __restrict__ Rout)        // MROWS x DDIM (bf16 residual)
{
  __shared__ __align__(16) unsigned short As[2 * 256 * 64];
  __shared__ __align__(16) unsigned short Bs[2 * 256 * 64];

  const int tid  = threadIdx.x;
  const int lane = tid & 63;
  const int wave = tid >> 6;

  // XCD-aware bijective swizzle (nwg=1024, %8==0)
  const int bid = blockIdx.x;
  const int wg  = (bid & 7) * 128 + (bid >> 3);
  const int bm  = wg >> 4;          // 0..63
  const int bn  = wg & 15;          // 0..15
  const int brow0 = bm * 256;
  const int bcol0 = bn * 256;

  const int srow  = tid >> 3;
  const int sslot = (tid & 7) ^ (srow & 7);
  const unsigned short* pA = Abf + (size_t)(brow0 + srow) * KDIM + sslot * 8;
  const unsigned short* pB = Bbf + (size_t)(bcol0 + srow) * KDIM + sslot * 8;
  const int ldst = wave * 512;

  const int wm   = wave >> 2;       // 0..1
  const int wn   = wave & 3;        // 0..3
  const int frow = lane & 15;
  const int kgrp = lane >> 4;       // 0..3

#define SA(d, kk, c) gload16(pA + (size_t)(c)*64*KDIM + (kk)*64, As + (d)*16384 + (c)*4096 + ldst)
#define SB(d, kk, c) gload16(pB + (size_t)(c)*64*KDIM + (kk)*64, Bs + (d)*16384 + (c)*4096 + ldst)
#define RD_A(mf, kc) (*(const bf16x8*)(Ard + (wm*128 + (mf)*16 + frow)*64 + ((((kc)*4 + kgrp) ^ (frow & 7)) << 3)))
#define RD_B(j, kc)  (*(const bf16x8*)(Brd + (wn*64  + (j)*16  + frow)*64 + ((((kc)*4 + kgrp) ^ (frow & 7)) << 3)))

  f32x4 acc[8][4] = {};

  // prologue: tile0 full -> buf0; tile1 {B01, A02, B23} -> buf1
  SA(0,0,0); SA(0,0,1); SA(0,0,2); SA(0,0,3);
  SB(0,0,0); SB(0,0,1); SB(0,0,2); SB(0,0,3);
  SB(1,1,0); SB(1,1,1);
  SA(1,1,0); SA(1,1,2);
  SB(1,1,2); SB(1,1,3);
  asm volatile("s_waitcnt vmcnt(6)" ::: "memory");
  __builtin_amdgcn_sched_barrier(0);
  bar();

  for (int kt = 0; kt < NKT; ++kt) {
    const int d = kt & 1;
    const unsigned short* Ard = As + d * 16384;
    const unsigned short* Brd = Bs + d * 16384;

    bf16x8 bv[4][2], af0[2], af1[2];

    // ---- phase 1 (quadrant 0): 8 B-reads + 4 A-reads | stage A13 of kt+1 ---
#pragma unroll
    for (int j = 0; j < 4; ++j) { bv[j][0] = RD_B(j, 0); bv[j][1] = RD_B(j, 1); }
    af0[0] = RD_A(0, 0); af0[1] = RD_A(0, 1);
    af1[0] = RD_A(1, 0); af1[1] = RD_A(1, 1);
    if (kt < NKT - 1) { SA(d ^ 1, kt + 1, 1); SA(d ^ 1, kt + 1, 3); }
    bar();
    LGKM0;
    __builtin_amdgcn_s_setprio(1);
#pragma unroll
    for (int j = 0; j < 4; ++j) {
      acc[0][j] = __builtin_amdgcn_mfma_f32_16x16x32_bf16(af0[0], bv[j][0], acc[0][j], 0, 0, 0);
      acc[0][j] = __builtin_amdgcn_mfma_f32_16x16x32_bf16(af0[1], bv[j][1], acc[0][j], 0, 0, 0);
      acc[1][j] = __builtin_amdgcn_mfma_f32_16x16x32_bf16(af1[0], bv[j][0], acc[1][j], 0, 0, 0);
      acc[1][j] = __builtin_amdgcn_mfma_f32_16x16x32_bf16(af1[1], bv[j][1], acc[1][j], 0, 0, 0);
    }
    __builtin_amdgcn_s_setprio(0);
    __builtin_amdgcn_sched_barrier(0);
    bar();

    // ---- phase 2 (quadrant 1): 4 A-reads | stage B01 of kt+2 ---------------
    af0[0] = RD_A(2, 0); af0[1] = RD_A(2, 1);
    af1[0] = RD_A(3, 0); af1[1] = RD_A(3, 1);
    if (kt < NKT - 2) { SB(d, kt + 2, 0); SB(d, kt + 2, 1); }
    bar();
    LGKM0;
    __builtin_amdgcn_s_setprio(1);
#pragma unroll
    for (int j = 0; j < 4; ++j) {
      acc[2][j] = __builtin_amdgcn_mfma_f32_16x16x32_bf16(af0[0], bv[j][0], acc[2][j], 0, 0, 0);
      acc[2][j] = __builtin_amdgcn_mfma_f32_16x16x32_bf16(af0[1], bv[j][1], acc[2][j], 0, 0, 0);
      acc[3][j] = __builtin_amdgcn_mfma_f32_16x16x32_bf16(af1[0], bv[j][0], acc[3][j], 0, 0, 0);
      acc[3][j] = __builtin_amdgcn_mfma_f32_16x16x32_bf16(af1[1], bv[j][1], acc[3][j], 0, 0, 0);
    }
    __builtin_amdgcn_s_setprio(0);
    __builtin_amdgcn_sched_barrier(0);
    bar();

    // ---- phase 3 (quadrant 2): 4 A-reads | stage A02 of kt+2 ---------------
    af0[0] = RD_A(4, 0); af0[1] = RD_A(4, 1);
    af1[0] = RD_A(5, 0); af1[1] = RD_A(5, 1);
    if (kt < NKT - 2) { SA(d, kt + 2, 0); SA(d, kt + 2, 2); }
    bar();
    LGKM0;
    __builtin_amdgcn_s_setprio(1);
#pragma unroll
    for (int j = 0; j < 4; ++j) {
      acc[4][j] = __builtin_amdgcn_mfma_f32_16x16x32_bf16(af0[0], bv[j][0], acc[4][j], 0, 0, 0);
      acc[4][j] = __builtin_amdgcn_mfma_f32_16x16x32_bf16(af0[1], bv[j][1], acc[4][j], 0, 0, 0);
      acc[5][j] = __builtin_amdgcn_mfma_f32_16x16x32_bf16(af1[0], bv[j][0], acc[5][j], 0, 0, 0);
      acc[5][j] = __builtin_amdgcn_mfma_f32_16x16x32_bf16(af1[1], bv[j][1], acc[5][j], 0, 0, 0);
    }
    __builtin_amdgcn_s_setprio(0);
    __builtin_amdgcn_sched_barrier(0);
    bar();

    // ---- phase 4 (quadrant 3): 4 A-reads | stage B23 of kt+2 | vmcnt -------
    af0[0] = RD_A(6, 0); af0[1] = RD_A(6, 1);
    af1[0] = RD_A(7, 0); af1[1] = RD_A(7, 1);
    if (kt < NKT - 2) { SB(d, kt + 2, 2); SB(d, kt + 2, 3); }
    bar();
    LGKM0;
    __builtin_amdgcn_s_setprio(1);
#pragma unroll
    for (int j = 0; j < 4; ++j) {
      acc[6][j] = __builtin_amdgcn_mfma_f32_16x16x32_bf16(af0[0], bv[j][0], acc[6][j], 0, 0, 0);
      acc[6][j] = __builtin_amdgcn_mfma_f32_16x16x32_bf16(af0[1], bv[j][1], acc[6][j], 0, 0, 0);
      acc[7][j] = __builtin_amdgcn_mfma_f32_16x16x32_bf16(af1[0], bv[j][0], acc[7][j], 0, 0, 0);
      acc[7][j] = __builtin_amdgcn_mfma_f32_16x16x32_bf16(af1[1], bv[j][1], acc[7][j], 0, 0, 0);
    }
    __builtin_amdgcn_s_setprio(0);
    if (kt < NKT - 2) { asm volatile("s_waitcnt vmcnt(6)" ::: "memory"); }
    else              { asm volatile("s_waitcnt vmcnt(0)" ::: "memory"); }
    __builtin_amdgcn_sched_barrier(0);
    bar();
  }

  // C write: col = lane&15, row = (lane>>4)*4 + reg  [verified r1-r3]
  unsigned short* Cb = (bn < 8) ? Tout : Rout;
  const int c0 = (bn < 8) ? bcol0 : (bcol0 - 2048);
#pragma unroll
  for (int i = 0; i < 8; ++i) {
    const int r0 = brow0 + wm * 128 + i * 16 + kgrp * 4;
#pragma unroll
    for (int j = 0; j < 4; ++j) {
      const int col = c0 + wn * 64 + j * 16 + frow;
#pragma unroll
      for (int r = 0; r < 4; ++r)
        Cb[(size_t)(r0 + r) * DDIM + col] = f2bf(acc[i][j][r]);
    }
  }
#undef SA
#undef SB
#undef RD_A
#undef RD_B
}

// ---------------- epilogue v2b: j-grouped rows, register-cached side data ---
// Rows with the same basis index j (row ≡ j mod 64) share gamma⊙B[j], At[j].
// Each WAVE spans the full 2048-wide row (col = l*4 + 256*c), so after the
// intra-wave shfl reduction every wave already holds the COMPLETE SG/SBB —
// no cross-wave reduction (round-5 bug: summing 8 waves' identical full sums
// gave 8×SG). No barriers at all; waves fully independent.
//   scalar = rstd·(Σ T·G − mean·SG) + SBB ; out = scalar·At[j] + R
__global__ __launch_bounds__(512) void epilogue(
    const unsigned short* __restrict__ T, const unsigned short* __restrict__ R,
    const float* __restrict__ Bb, const float* __restrict__ At,
    const float* __restrict__ gam, const float* __restrict__ bet,
    float* __restrict__ out)
{
  const int b   = blockIdx.x;        // 0..1023
  const int j   = b & 63;
  const int seg = b >> 6;            // 0..15
  const int wv  = threadIdx.x >> 6;  // 0..7
  const int l   = threadIdx.x & 63;
  const size_t jb = (size_t)j * DDIM;

  float4 G[8], A4[8];
  float sgp = 0.f, sbbp = 0.f;
#pragma unroll
  for (int c = 0; c < 8; ++c) {
    const int col = l * 4 + 256 * c;
    float4 g = *(const float4*)(gam + col);
    float4 w = *(const float4*)(Bb + jb + col);
    float4 be = *(const float4*)(bet + col);
    A4[c] = *(const float4*)(At + jb + col);
    G[c].x = g.x * w.x; G[c].y = g.y * w.y; G[c].z = g.z * w.z; G[c].w = g.w * w.w;
    sgp  += G[c].x + G[c].y + G[c].z + G[c].w;
    sbbp += be.x * w.x + be.y * w.y + be.z * w.z + be.w * w.w;
  }
#pragma unroll
  for (int off = 32; off > 0; off >>= 1) {
    sgp  += __shfl_xor(sgp,  off);
    sbbp += __shfl_xor(sbbp, off);
  }
  const float SG = sgp;    // full sum per wave (wave spans the whole row)
  const float SBB = sbbp;

#pragma unroll
  for (int rr = 0; rr < 2; ++rr) {
    const int k = seg * 16 + wv * 2 + rr;           // 0..255
    const size_t rowb = (size_t)(j + 64 * k) * DDIM;
    float s1 = 0.f, s2 = 0.f, s3 = 0.f;
#pragma unroll
    for (int c = 0; c < 8; ++c) {
      const int col = l * 4 + 256 * c;
      ushort4 tv = *(const ushort4*)(T + rowb + col);
      float t0 = bf2f(tv.x), t1 = bf2f(tv.y), t2 = bf2f(tv.z), t3 = bf2f(tv.w);
      s1 += t0 + t1 + t2 + t3;
      s2 += t0 * t0 + t1 * t1 + t2 * t2 + t3 * t3;
      s3 += t0 * G[c].x + t1 * G[c].y + t2 * G[c].z + t3 * G[c].w;
    }
#pragma unroll
    for (int off = 32; off > 0; off >>= 1) {
      s1 += __shfl_xor(s1, off);
      s2 += __shfl_xor(s2, off);
      s3 += __shfl_xor(s3, off);
    }
    const float mean = s1 * (1.0f / 2048.0f);
    const float var  = s2 * (1.0f / 2048.0f) - mean * mean;
    const float rstd = rsqrtf(var + EPSLN);
    const float scalar = rstd * (s3 - mean * SG) + SBB;
#pragma unroll
    for (int c = 0; c < 8; ++c) {
      const int col = l * 4 + 256 * c;
      ushort4 rv = *(const ushort4*)(R + rowb + col);
      float4 o;
      o.x = scalar * A4[c].x + bf2f(rv.x);
      o.y = scalar * A4[c].y + bf2f(rv.y);
      o.z = scalar * A4[c].z + bf2f(rv.z);
      o.w = scalar * A4[c].w + bf2f(rv.w);
      *(float4*)(out + rowb + col) = o;
    }
  }
}

// ---------------- launch ------------------------------------------------------
extern "C" void kernel_launch(void* const* d_in, const int* in_sizes, int n_in,
                              void* d_out, int out_size, void* d_ws, size_t ws_size,
                              hipStream_t stream) {
  const float* x      = (const float*)d_in[0];
  const float* W      = (const float*)d_in[1];
  const float* Wres   = (const float*)d_in[2];
  const float* gamma  = (const float*)d_in[3];
  const float* beta   = (const float*)d_in[4];
  const float* Acoeff = (const float*)d_in[5];
  const float* Bbasis = (const float*)d_in[6];
  float* out = (float*)d_out;
  char* ws = (char*)d_ws;

  // ws layout (bytes):
  //   [0,           67108864)  x_bf16   16384x2048 bf16
  //   [67108864,    83886080)  Wc_bf16  4096x2048 bf16 (W then W_res)
  //   [83886080,   150994944)  T        16384x2048 bf16
  //   [150994944,  218103808)  Rbf      16384x2048 bf16 (residual)
  //   [218103808,  218628096)  At       64x2048 f32
  unsigned short* xbf = (unsigned short*)ws;
  unsigned short* Wc  = (unsigned short*)(ws + 67108864);
  unsigned short* T   = (unsigned short*)(ws + 83886080);
  unsigned short* Rbf = (unsigned short*)(ws + 150994944);
  float* At           = (float*)(ws + 218103808);

  prep<<<3136, 256, 0, stream>>>(x, W, Wres, Acoeff, xbf, Wc, At);

  gemm_dual<<<1024, 512, 0, stream>>>(xbf, Wc, T, Rbf);

  epilogue<<<1024, 512, 0, stream>>>(T, Rbf, Bbasis, At, gamma, beta, out);
}